// Round 7
// baseline (564.779 us; speedup 1.0000x reference)
//
#include <hip/hip_runtime.h>
#include <hip/hip_fp16.h>

#define T_TOKENS 2048
#define H_DIM    2048
#define I_DIM    1408
#define E_NUM    8

typedef _Float16 f16;
typedef __attribute__((ext_vector_type(8))) _Float16 f16x8;
typedef __attribute__((ext_vector_type(4))) float    floatx4;
typedef __attribute__((ext_vector_type(4))) unsigned uintx4;

// ---------------- ws layout (bytes) ----------------
static const size_t OFF_COUNTS = 0;
static const size_t OFF_LISTS  = 256;
static const size_t OFF_WLISTS = OFF_LISTS + (size_t)T_TOKENS * E_NUM * 4;        // 65792
static const size_t OFF_XB     = 131328;                                          // [T][H] f16 = 8.39 MB
static const size_t OFF_ACT    = OFF_XB + (size_t)T_TOKENS * H_DIM * 2;           // [2T][I] f16 = 11.5 MB
static const size_t OFF_GUPK   = OFF_ACT + (size_t)2 * T_TOKENS * I_DIM * 2;      // nib gu = 23.1 MB
static const size_t OFF_DNPK   = OFF_GUPK + (size_t)E_NUM * 44 * 32 * 64 * 8 * 4; // nib dn = 11.5 MB
static const size_t OFF_TMP    = OFF_DNPK + (size_t)E_NUM * 32 * 22 * 64 * 8 * 4; // f32 [2T][H] = 33.6 MB

// Nibble placement within each 8-value dword: k=j stored at nibble (j>>1)+((j&1)<<2),
// so ((d>>4i)&0x000F000F)|0x64006400 yields fp16 pairs (k=2i, k=2i+1) in order.

// ---------------- pack gate_up: nibble-pack + tile (N=32 icols -> 64 rows) + swizzle ----------------
__global__ __launch_bounds__(256) void pack_gu_kernel(const int* __restrict__ q,
                                                      unsigned* __restrict__ out)
{
    const int b = blockIdx.x;              // global gate_up row, 0..22527
    const int g = threadIdx.x;             // output dword (8 k-values)
    const int4* qp = reinterpret_cast<const int4*>(q + (size_t)b * H_DIM) + g * 2;
    int4 a = qp[0], c = qp[1];
    unsigned d = (unsigned)(a.x & 15)        | ((unsigned)(a.z & 15) << 4)  |
                 ((unsigned)(c.x & 15) << 8) | ((unsigned)(c.z & 15) << 12) |
                 ((unsigned)(a.y & 15) << 16)| ((unsigned)(a.w & 15) << 20) |
                 ((unsigned)(c.y & 15) << 24)| ((unsigned)(c.w & 15) << 28);
    const int e = b / 2816;
    const int grow = b - e * 2816;
    const int is_up = grow >= I_DIM;
    const int icol  = grow - (is_up ? I_DIM : 0);
    const int nt    = icol >> 5;                                  // 44 n-tiles of 32 I-cols
    const int r     = ((((icol >> 4) & 1) * 2 + is_up) * 16) + (icol & 15);  // 0..63
    const int kt    = g >> 3, gg = g & 7;
    out[((((size_t)e * 44 + nt) * 32 + kt) * 64 + r) * 8 + (gg ^ (r & 7))] = d;
}

// ---------------- pack down: nibble-pack + tile (N=64) + swizzle ----------------
__global__ __launch_bounds__(256) void pack_dn_kernel(const int* __restrict__ q,
                                                      unsigned* __restrict__ out)
{
    const int b = blockIdx.x;              // e*2048 + H-row
    const int t = threadIdx.x;
    if (t >= 176) return;
    const int4* qp = reinterpret_cast<const int4*>(q + (size_t)b * I_DIM) + t * 2;
    int4 a = qp[0], c = qp[1];
    unsigned d = (unsigned)(a.x & 15)        | ((unsigned)(a.z & 15) << 4)  |
                 ((unsigned)(c.x & 15) << 8) | ((unsigned)(c.z & 15) << 12) |
                 ((unsigned)(a.y & 15) << 16)| ((unsigned)(a.w & 15) << 20) |
                 ((unsigned)(c.y & 15) << 24)| ((unsigned)(c.w & 15) << 28);
    const int e = b >> 11;
    const int grow = b & 2047;
    const int nt = grow >> 6;              // 32 n-tiles of 64 H-cols
    const int r  = grow & 63;
    const int kt = t >> 3, gg = t & 7;
    out[((((size_t)e * 32 + nt) * 22 + kt) * 64 + r) * 8 + (gg ^ (r & 7))] = d;
}

// ---------------- x f32 -> f16 ----------------
__global__ void xconv_kernel(const float* __restrict__ x, f16* __restrict__ xb)
{
    int i = blockIdx.x * blockDim.x + threadIdx.x;
    const float4* x4 = reinterpret_cast<const float4*>(x) + (size_t)i * 2;
    float4 v0 = x4[0], v1 = x4[1];
    f16x8 bv;
    bv[0] = (f16)v0.x; bv[1] = (f16)v0.y; bv[2] = (f16)v0.z; bv[3] = (f16)v0.w;
    bv[4] = (f16)v1.x; bv[5] = (f16)v1.y; bv[6] = (f16)v1.z; bv[7] = (f16)v1.w;
    *reinterpret_cast<f16x8*>(xb + (size_t)i * 8) = bv;
}

// ---------------- routing ----------------
__global__ void router_kernel(const float* __restrict__ logits,
                              int* __restrict__ counts,
                              int* __restrict__ lists,
                              float* __restrict__ wlists)
{
    int t = blockIdx.x * blockDim.x + threadIdx.x;
    if (t >= T_TOKENS) return;
    const float* l = logits + (size_t)t * E_NUM;
    float v0 = -1e30f, v1 = -1e30f;
    int i0 = 0, i1 = 0;
    #pragma unroll
    for (int e = 0; e < E_NUM; ++e) {
        float v = l[e];
        if (v > v0) { v1 = v0; i1 = i0; v0 = v; i0 = e; }
        else if (v > v1) { v1 = v; i1 = e; }
    }
    float w0 = 1.f / (1.f + __expf(v1 - v0));
    float w1 = 1.f - w0;
    int p0 = atomicAdd(&counts[i0], 1);
    lists[i0 * T_TOKENS + p0] = t * 2 + 0;
    wlists[i0 * T_TOKENS + p0] = w0;
    int p1 = atomicAdd(&counts[i1], 1);
    lists[i1 * T_TOKENS + p1] = t * 2 + 1;
    wlists[i1 * T_TOKENS + p1] = w1;
}

// exact zero-point dequant: (0x6400|n)=1024+n exact; -1032 exact; * s -> relative error only
__device__ __forceinline__ f16x8 dq8(unsigned d, __half2 s2)
{
    const __half2 off = __floats2half2_rn(1032.f, 1032.f);
    unsigned t0 = (d         & 0x000F000Fu) | 0x64006400u;
    unsigned t1 = ((d >> 4)  & 0x000F000Fu) | 0x64006400u;
    unsigned t2 = ((d >> 8)  & 0x000F000Fu) | 0x64006400u;
    unsigned t3 = ((d >> 12) & 0x000F000Fu) | 0x64006400u;
    uintx4 w;
    w.x = __builtin_bit_cast(unsigned, __hmul2(__hsub2(__builtin_bit_cast(__half2, t0), off), s2));
    w.y = __builtin_bit_cast(unsigned, __hmul2(__hsub2(__builtin_bit_cast(__half2, t1), off), s2));
    w.z = __builtin_bit_cast(unsigned, __hmul2(__hsub2(__builtin_bit_cast(__half2, t2), off), s2));
    w.w = __builtin_bit_cast(unsigned, __hmul2(__hsub2(__builtin_bit_cast(__half2, t3), off), s2));
    return __builtin_bit_cast(f16x8, w);
}

// ---------------- GEMM1: 128m x 32i tile (64 interleaved gate/up rows), fused dequant+SwiGLU ----------------
// grid (44, 16, 8): 44 n-tiles -> ~1408 useful blocks (5.5/CU) for latency hiding.
__global__ __launch_bounds__(256) void gemm1_kernel(
    const f16*      __restrict__ xb,
    const unsigned* __restrict__ qpk,
    const float*    __restrict__ sc,     // [E][2816][16]
    const int*      __restrict__ counts,
    const int*      __restrict__ lists,
    f16*            __restrict__ act)
{
    const int e   = blockIdx.z;
    const int cnt = counts[e];
    const int m0  = blockIdx.y * 128;
    if (m0 >= cnt) return;
    const int nt  = blockIdx.x;

    __shared__ __align__(16) f16 Al[8192];       // 128 x 64
    __shared__ unsigned Blu[512];                // 64 rows x 8 dwords (swizzled)
    __shared__ float scl[64 * 17];               // padded
    __shared__ int meta[128];

    const int tid = threadIdx.x;
    if (tid < 128) {
        int m = m0 + tid;
        meta[tid] = lists[e * T_TOKENS + (m < cnt ? m : 0)];
    }
    // stage scales: 64 rows x 16 groups
    for (int i = tid; i < 1024; i += 256) {
        int r = i >> 4, grp = i & 15;
        int tt = r >> 4;                          // 0..3: {gate,up} x colgrp
        int grow = ((tt & 1) ? I_DIM : 0) + nt * 32 + (tt >> 1) * 16 + (r & 15);
        scl[r * 17 + grp] = sc[(size_t)(e * 2816 + grow) * 16 + grp];
    }
    __syncthreads();

    const int lane = tid & 63;
    const int wv = tid >> 6;
    const int wm = wv >> 1, wn = wv & 1;   // wm: M half; wn: 32-row B half (one gate/up pair)

    int    aoff[4];
    size_t agbl[4];
    #pragma unroll
    for (int j = 0; j < 4; ++j) {
        int g = tid + 256 * j;
        int arow = g >> 3, cg = g & 7;
        aoff[j] = arow * 64 + ((cg ^ (arow & 7)) * 8);
        agbl[j] = (size_t)(meta[arow] >> 1) * H_DIM + cg * 8;
    }
    const unsigned* bt = qpk + ((size_t)e * 44 + nt) * (32 * 512);

    floatx4 acc[4][2];
    #pragma unroll
    for (int i = 0; i < 4; ++i)
        #pragma unroll
        for (int j = 0; j < 2; ++j)
            acc[i][j] = (floatx4){0.f, 0.f, 0.f, 0.f};

    for (int kt = 0; kt < 32; ++kt) {
        #pragma unroll
        for (int j = 0; j < 4; ++j) {
            f16x8 v = *reinterpret_cast<const f16x8*>(xb + agbl[j] + kt * 64);
            *reinterpret_cast<f16x8*>(&Al[aoff[j]]) = v;
        }
        const unsigned* bsrc = bt + kt * 512;
        #pragma unroll
        for (int j = 0; j < 2; ++j)
            Blu[tid + j * 256] = bsrc[tid + j * 256];
        __syncthreads();

        const int grp = kt >> 1;
        #pragma unroll
        for (int ks = 0; ks < 2; ++ks) {
            const int gidx = ks * 4 + (lane >> 4);
            f16x8 af[4], bf[2];
            #pragma unroll
            for (int mt = 0; mt < 4; ++mt) {
                int ra = wm * 64 + mt * 16 + (lane & 15);
                af[mt] = *reinterpret_cast<const f16x8*>(&Al[ra * 64 + ((gidx ^ (ra & 7)) * 8)]);
            }
            #pragma unroll
            for (int ntf = 0; ntf < 2; ++ntf) {
                int rb = wn * 32 + ntf * 16 + (lane & 15);
                __half2 s2 = __float2half2_rn(scl[rb * 17 + grp]);
                unsigned d = Blu[rb * 8 + (gidx ^ (rb & 7))];
                bf[ntf] = dq8(d, s2);
            }
            #pragma unroll
            for (int mt = 0; mt < 4; ++mt)
                #pragma unroll
                for (int ntf = 0; ntf < 2; ++ntf)
                    acc[mt][ntf] = __builtin_amdgcn_mfma_f32_16x16x32_f16(af[mt], bf[ntf], acc[mt][ntf], 0, 0, 0);
        }
        __syncthreads();
    }

    // epilogue: SwiGLU (ntf=0 gate, ntf=1 up, col-group = wn) + scatter
    const int rbase = (lane >> 4) * 4;
    const int cn = lane & 15;
    #pragma unroll
    for (int mt = 0; mt < 4; ++mt) {
        floatx4 g = acc[mt][0];
        floatx4 u = acc[mt][1];
        int col = nt * 32 + wn * 16 + cn;
        #pragma unroll
        for (int r = 0; r < 4; ++r) {
            int lrow = wm * 64 + mt * 16 + rbase + r;
            if (m0 + lrow < cnt) {
                float gate = g[r], up = u[r];
                float a = gate / (1.f + __expf(-gate)) * up;
                act[(size_t)meta[lrow] * I_DIM + col] = (f16)a;
            }
        }
    }
}

// ---------------- GEMM2: 128m x 64h tile, fused dequant, coalesced tmp ----------------
// grid (32, 16, 8): ~1024 useful blocks (4/CU).
__global__ __launch_bounds__(256) void gemm2_kernel(
    const f16*      __restrict__ act,
    const unsigned* __restrict__ qpk,
    const float*    __restrict__ sc,     // [E][2048][11]
    const int*      __restrict__ counts,
    const int*      __restrict__ lists,
    const float*    __restrict__ wlists,
    float*          __restrict__ tmp)
{
    const int e   = blockIdx.z;
    const int cnt = counts[e];
    const int m0  = blockIdx.y * 128;
    if (m0 >= cnt) return;
    const int nt  = blockIdx.x;

    __shared__ __align__(16) f16 Al[8192];
    __shared__ unsigned Blu[512];
    __shared__ float scl[64 * 12];
    __shared__ int   meta[128];
    __shared__ float wmeta[128];

    const int tid = threadIdx.x;
    if (tid < 128) {
        int m = m0 + tid;
        int mm = (m < cnt) ? m : 0;
        meta[tid]  = lists[e * T_TOKENS + mm];
        wmeta[tid] = wlists[e * T_TOKENS + mm];
    }
    for (int i = tid; i < 704; i += 256) {
        int r = i / 11, grp = i - r * 11;
        scl[r * 12 + grp] = sc[(size_t)(e * 2048 + nt * 64 + r) * 11 + grp];
    }
    __syncthreads();

    const int lane = tid & 63;
    const int wv = tid >> 6;
    const int wm = wv >> 1, wn = wv & 1;

    int    aoff[4];
    size_t agbl[4];
    #pragma unroll
    for (int j = 0; j < 4; ++j) {
        int g = tid + 256 * j;
        int arow = g >> 3, cg = g & 7;
        aoff[j] = arow * 64 + ((cg ^ (arow & 7)) * 8);
        agbl[j] = (size_t)meta[arow] * I_DIM + cg * 8;
    }
    const unsigned* bt = qpk + ((size_t)e * 32 + nt) * (22 * 512);

    floatx4 acc[4][2];
    #pragma unroll
    for (int i = 0; i < 4; ++i)
        #pragma unroll
        for (int j = 0; j < 2; ++j)
            acc[i][j] = (floatx4){0.f, 0.f, 0.f, 0.f};

    for (int kt = 0; kt < 22; ++kt) {
        #pragma unroll
        for (int j = 0; j < 4; ++j) {
            f16x8 v = *reinterpret_cast<const f16x8*>(act + agbl[j] + kt * 64);
            *reinterpret_cast<f16x8*>(&Al[aoff[j]]) = v;
        }
        const unsigned* bsrc = bt + kt * 512;
        #pragma unroll
        for (int j = 0; j < 2; ++j)
            Blu[tid + j * 256] = bsrc[tid + j * 256];
        __syncthreads();

        const int grp = kt >> 1;
        #pragma unroll
        for (int ks = 0; ks < 2; ++ks) {
            const int gidx = ks * 4 + (lane >> 4);
            f16x8 af[4], bf[2];
            #pragma unroll
            for (int mt = 0; mt < 4; ++mt) {
                int ra = wm * 64 + mt * 16 + (lane & 15);
                af[mt] = *reinterpret_cast<const f16x8*>(&Al[ra * 64 + ((gidx ^ (ra & 7)) * 8)]);
            }
            #pragma unroll
            for (int ntf = 0; ntf < 2; ++ntf) {
                int rb = wn * 32 + ntf * 16 + (lane & 15);
                __half2 s2 = __float2half2_rn(scl[rb * 12 + grp]);
                unsigned d = Blu[rb * 8 + (gidx ^ (rb & 7))];
                bf[ntf] = dq8(d, s2);
            }
            #pragma unroll
            for (int mt = 0; mt < 4; ++mt)
                #pragma unroll
                for (int ntf = 0; ntf < 2; ++ntf)
                    acc[mt][ntf] = __builtin_amdgcn_mfma_f32_16x16x32_f16(af[mt], bf[ntf], acc[mt][ntf], 0, 0, 0);
        }
        __syncthreads();
    }

    const int rbase = (lane >> 4) * 4;
    const int cn = lane & 15;
    #pragma unroll
    for (int mt = 0; mt < 4; ++mt) {
        #pragma unroll
        for (int ntf = 0; ntf < 2; ++ntf) {
            floatx4 v = acc[mt][ntf];
            int col = nt * 64 + wn * 32 + ntf * 16 + cn;
            #pragma unroll
            for (int r = 0; r < 4; ++r) {
                int lrow = wm * 64 + mt * 16 + rbase + r;
                if (m0 + lrow < cnt) {
                    tmp[(size_t)meta[lrow] * H_DIM + col] = wmeta[lrow] * v[r];
                }
            }
        }
    }
}

// ---------------- finalize: out[t] = tmp[2t] + tmp[2t+1] ----------------
__global__ void finalize_kernel(const float* __restrict__ tmp, float* __restrict__ out)
{
    int i4 = blockIdx.x * blockDim.x + threadIdx.x;
    int t  = i4 >> 9;
    int h  = (i4 & 511) * 4;
    float4 a = *reinterpret_cast<const float4*>(tmp + ((size_t)2 * t) * H_DIM + h);
    float4 b = *reinterpret_cast<const float4*>(tmp + ((size_t)(2 * t + 1)) * H_DIM + h);
    float4 o;
    o.x = a.x + b.x; o.y = a.y + b.y; o.z = a.z + b.z; o.w = a.w + b.w;
    *reinterpret_cast<float4*>(out + (size_t)t * H_DIM + h) = o;
}

extern "C" void kernel_launch(void* const* d_in, const int* in_sizes, int n_in,
                              void* d_out, int out_size, void* d_ws, size_t ws_size,
                              hipStream_t stream)
{
    const float* router_logits = (const float*)d_in[0];
    const float* x             = (const float*)d_in[1];
    const int*   gu_q          = (const int*)d_in[2];
    const float* gu_s          = (const float*)d_in[3];
    const int*   dn_q          = (const int*)d_in[4];
    const float* dn_s          = (const float*)d_in[5];
    float* out = (float*)d_out;

    char* ws = (char*)d_ws;
    int*      counts = (int*)(ws + OFF_COUNTS);
    int*      lists  = (int*)(ws + OFF_LISTS);
    float*    wlists = (float*)(ws + OFF_WLISTS);
    f16*      xb     = (f16*)(ws + OFF_XB);
    f16*      act    = (f16*)(ws + OFF_ACT);
    unsigned* gu_pk  = (unsigned*)(ws + OFF_GUPK);
    unsigned* dn_pk  = (unsigned*)(ws + OFF_DNPK);
    float*    tmp    = (float*)(ws + OFF_TMP);

    hipMemsetAsync(counts, 0, E_NUM * sizeof(int), stream);

    pack_gu_kernel<<<E_NUM * 2816, 256, 0, stream>>>(gu_q, gu_pk);
    pack_dn_kernel<<<E_NUM * 2048, 256, 0, stream>>>(dn_q, dn_pk);
    xconv_kernel<<<T_TOKENS * H_DIM / 8 / 256, 256, 0, stream>>>(x, xb);
    router_kernel<<<T_TOKENS / 256, 256, 0, stream>>>(router_logits, counts, lists, wlists);

    gemm1_kernel<<<dim3(44, 16, 8), 256, 0, stream>>>(xb, gu_pk, gu_s, counts, lists, act);
    gemm2_kernel<<<dim3(32, 16, 8), 256, 0, stream>>>(act, dn_pk, dn_s, counts, lists, wlists, tmp);
    finalize_kernel<<<4096, 256, 0, stream>>>(tmp, out);
}

// Round 8
// 537.671 us; speedup vs baseline: 1.0504x; 1.0504x over previous
//
#include <hip/hip_runtime.h>
#include <hip/hip_fp16.h>

#define T_TOKENS 2048
#define H_DIM    2048
#define I_DIM    1408
#define E_NUM    8

typedef _Float16 f16;
typedef __attribute__((ext_vector_type(8))) _Float16 f16x8;
typedef __attribute__((ext_vector_type(4))) float    floatx4;
typedef __attribute__((ext_vector_type(4))) unsigned uintx4;

// ---------------- ws layout (bytes) ----------------
static const size_t OFF_COUNTS = 0;
static const size_t OFF_LISTS  = 256;
static const size_t OFF_WLISTS = OFF_LISTS + (size_t)T_TOKENS * E_NUM * 4;        // 65792
static const size_t OFF_XB     = 131328;                                          // [T][H] f16 = 8.39 MB
static const size_t OFF_ACT    = OFF_XB + (size_t)T_TOKENS * H_DIM * 2;           // [2T][I] f16 = 11.5 MB
static const size_t OFF_GUPK   = OFF_ACT + (size_t)2 * T_TOKENS * I_DIM * 2;      // nib gu = 23.1 MB
static const size_t OFF_DNPK   = OFF_GUPK + (size_t)E_NUM * 22 * 32 * 128 * 8 * 4;// nib dn = 11.5 MB
static const size_t OFF_TMP    = OFF_DNPK + (size_t)E_NUM * 32 * 22 * 64 * 8 * 4; // f32 [2T][H] = 33.6 MB

// Nibble placement within each 8-value dword: k=j stored at nibble (j>>1)+((j&1)<<2),
// so ((d>>4i)&0x000F000F)|0x64006400 yields fp16 pairs (k=2i, k=2i+1) in order.

// ---------------- pack gate_up: tile 64 I-cols -> 128 interleaved gate/up rows ----------------
__global__ __launch_bounds__(256) void pack_gu_kernel(const int* __restrict__ q,
                                                      unsigned* __restrict__ out)
{
    const int b = blockIdx.x;              // global gate_up row, 0..22527
    const int g = threadIdx.x;             // output dword (8 k-values)
    const int4* qp = reinterpret_cast<const int4*>(q + (size_t)b * H_DIM) + g * 2;
    int4 a = qp[0], c = qp[1];
    unsigned d = (unsigned)(a.x & 15)        | ((unsigned)(a.z & 15) << 4)  |
                 ((unsigned)(c.x & 15) << 8) | ((unsigned)(c.z & 15) << 12) |
                 ((unsigned)(a.y & 15) << 16)| ((unsigned)(a.w & 15) << 20) |
                 ((unsigned)(c.y & 15) << 24)| ((unsigned)(c.w & 15) << 28);
    const int e = b / 2816;
    const int grow = b - e * 2816;
    const int is_up = grow >= I_DIM;
    const int icol  = grow - (is_up ? I_DIM : 0);
    const int nt    = icol >> 6;                                             // 22 n-tiles
    const int r     = ((((icol >> 4) & 3) * 2 + is_up) * 16) + (icol & 15);  // 0..127
    const int kt    = g >> 3, gg = g & 7;
    out[((((size_t)e * 22 + nt) * 32 + kt) * 128 + r) * 8 + (gg ^ (r & 7))] = d;
}

// ---------------- pack down: tile 64 H-cols ----------------
__global__ __launch_bounds__(256) void pack_dn_kernel(const int* __restrict__ q,
                                                      unsigned* __restrict__ out)
{
    const int b = blockIdx.x;              // e*2048 + H-row
    const int t = threadIdx.x;
    if (t >= 176) return;
    const int4* qp = reinterpret_cast<const int4*>(q + (size_t)b * I_DIM) + t * 2;
    int4 a = qp[0], c = qp[1];
    unsigned d = (unsigned)(a.x & 15)        | ((unsigned)(a.z & 15) << 4)  |
                 ((unsigned)(c.x & 15) << 8) | ((unsigned)(c.z & 15) << 12) |
                 ((unsigned)(a.y & 15) << 16)| ((unsigned)(a.w & 15) << 20) |
                 ((unsigned)(c.y & 15) << 24)| ((unsigned)(c.w & 15) << 28);
    const int e = b >> 11;
    const int grow = b & 2047;
    const int nt = grow >> 6;              // 32 n-tiles of 64 H-cols
    const int r  = grow & 63;
    const int kt = t >> 3, gg = t & 7;
    out[((((size_t)e * 32 + nt) * 22 + kt) * 64 + r) * 8 + (gg ^ (r & 7))] = d;
}

// ---------------- x f32 -> f16 ----------------
__global__ void xconv_kernel(const float* __restrict__ x, f16* __restrict__ xb)
{
    int i = blockIdx.x * blockDim.x + threadIdx.x;
    const float4* x4 = reinterpret_cast<const float4*>(x) + (size_t)i * 2;
    float4 v0 = x4[0], v1 = x4[1];
    f16x8 bv;
    bv[0] = (f16)v0.x; bv[1] = (f16)v0.y; bv[2] = (f16)v0.z; bv[3] = (f16)v0.w;
    bv[4] = (f16)v1.x; bv[5] = (f16)v1.y; bv[6] = (f16)v1.z; bv[7] = (f16)v1.w;
    *reinterpret_cast<f16x8*>(xb + (size_t)i * 8) = bv;
}

// ---------------- routing ----------------
__global__ void router_kernel(const float* __restrict__ logits,
                              int* __restrict__ counts,
                              int* __restrict__ lists,
                              float* __restrict__ wlists)
{
    int t = blockIdx.x * blockDim.x + threadIdx.x;
    if (t >= T_TOKENS) return;
    const float* l = logits + (size_t)t * E_NUM;
    float v0 = -1e30f, v1 = -1e30f;
    int i0 = 0, i1 = 0;
    #pragma unroll
    for (int e = 0; e < E_NUM; ++e) {
        float v = l[e];
        if (v > v0) { v1 = v0; i1 = i0; v0 = v; i0 = e; }
        else if (v > v1) { v1 = v; i1 = e; }
    }
    float w0 = 1.f / (1.f + __expf(v1 - v0));
    float w1 = 1.f - w0;
    int p0 = atomicAdd(&counts[i0], 1);
    lists[i0 * T_TOKENS + p0] = t * 2 + 0;
    wlists[i0 * T_TOKENS + p0] = w0;
    int p1 = atomicAdd(&counts[i1], 1);
    lists[i1 * T_TOKENS + p1] = t * 2 + 1;
    wlists[i1 * T_TOKENS + p1] = w1;
}

// exact zero-point dequant: (0x6400|n)=1024+n exact; -1032 exact; * s -> relative error only
__device__ __forceinline__ f16x8 dq8(unsigned d, __half2 s2)
{
    const __half2 off = __floats2half2_rn(1032.f, 1032.f);
    unsigned t0 = (d         & 0x000F000Fu) | 0x64006400u;
    unsigned t1 = ((d >> 4)  & 0x000F000Fu) | 0x64006400u;
    unsigned t2 = ((d >> 8)  & 0x000F000Fu) | 0x64006400u;
    unsigned t3 = ((d >> 12) & 0x000F000Fu) | 0x64006400u;
    uintx4 w;
    w.x = __builtin_bit_cast(unsigned, __hmul2(__hsub2(__builtin_bit_cast(__half2, t0), off), s2));
    w.y = __builtin_bit_cast(unsigned, __hmul2(__hsub2(__builtin_bit_cast(__half2, t1), off), s2));
    w.z = __builtin_bit_cast(unsigned, __hmul2(__hsub2(__builtin_bit_cast(__half2, t2), off), s2));
    w.w = __builtin_bit_cast(unsigned, __hmul2(__hsub2(__builtin_bit_cast(__half2, t3), off), s2));
    return __builtin_bit_cast(f16x8, w);
}

// ---------------- GEMM1: 128m x 64i, double-buffered + register prefetch, fused SwiGLU ----------------
__global__ __launch_bounds__(256) void gemm1_kernel(
    const f16*      __restrict__ xb,
    const unsigned* __restrict__ qpk,
    const float*    __restrict__ sc,     // [E][2816][16]
    const int*      __restrict__ counts,
    const int*      __restrict__ lists,
    f16*            __restrict__ act)
{
    const int e   = blockIdx.z;
    const int cnt = counts[e];
    const int m0  = blockIdx.y * 128;
    if (m0 >= cnt) return;
    const int nt  = blockIdx.x;

    __shared__ __align__(16) f16 Al[2][8192];    // 2 x 128 x 64
    __shared__ unsigned Blu[2][1024];            // 2 x (128 rows x 8 dwords, swizzled)
    __shared__ float scl[128 * 17];
    __shared__ int meta[128];

    const int tid = threadIdx.x;
    if (tid < 128) {
        int m = m0 + tid;
        meta[tid] = lists[e * T_TOKENS + (m < cnt ? m : 0)];
    }
    for (int i = tid; i < 2048; i += 256) {
        int r = i >> 4, grp = i & 15;
        int tt = r >> 4;
        int grow = ((tt & 1) ? I_DIM : 0) + nt * 64 + (tt >> 1) * 16 + (r & 15);
        scl[r * 17 + grp] = sc[(size_t)(e * 2816 + grow) * 16 + grp];
    }
    __syncthreads();

    const int lane = tid & 63;
    const int wv = tid >> 6;
    const int wm = wv >> 1, wn = wv & 1;

    int    aoff[4];
    size_t agbl[4];
    #pragma unroll
    for (int j = 0; j < 4; ++j) {
        int g = tid + 256 * j;
        int arow = g >> 3, cg = g & 7;
        aoff[j] = arow * 64 + ((cg ^ (arow & 7)) * 8);
        agbl[j] = (size_t)(meta[arow] >> 1) * H_DIM + cg * 8;
    }
    const unsigned* bt = qpk + ((size_t)e * 22 + nt) * (32 * 1024);

    floatx4 acc[4][4];
    #pragma unroll
    for (int i = 0; i < 4; ++i)
        #pragma unroll
        for (int j = 0; j < 4; ++j)
            acc[i][j] = (floatx4){0.f, 0.f, 0.f, 0.f};

    // prologue: tile 0 -> buf 0
    f16x8    areg[4];
    unsigned breg[4];
    #pragma unroll
    for (int j = 0; j < 4; ++j) areg[j] = *reinterpret_cast<const f16x8*>(xb + agbl[j]);
    #pragma unroll
    for (int j = 0; j < 4; ++j) breg[j] = bt[tid + j * 256];
    #pragma unroll
    for (int j = 0; j < 4; ++j) *reinterpret_cast<f16x8*>(&Al[0][aoff[j]]) = areg[j];
    #pragma unroll
    for (int j = 0; j < 4; ++j) Blu[0][tid + j * 256] = breg[j];
    __syncthreads();

    for (int kt = 0; kt < 32; ++kt) {
        const int cur = kt & 1;
        if (kt < 31) {   // prefetch next tile into registers (latency overlapped with compute)
            #pragma unroll
            for (int j = 0; j < 4; ++j)
                areg[j] = *reinterpret_cast<const f16x8*>(xb + agbl[j] + (kt + 1) * 64);
            #pragma unroll
            for (int j = 0; j < 4; ++j)
                breg[j] = bt[(kt + 1) * 1024 + tid + j * 256];
        }
        const int grp = kt >> 1;
        __half2 s2v[4];
        #pragma unroll
        for (int ntf = 0; ntf < 4; ++ntf)
            s2v[ntf] = __float2half2_rn(scl[(wn * 64 + ntf * 16 + (lane & 15)) * 17 + grp]);

        #pragma unroll
        for (int ks = 0; ks < 2; ++ks) {
            const int gidx = ks * 4 + (lane >> 4);
            f16x8 af[4], bf[4];
            #pragma unroll
            for (int mt = 0; mt < 4; ++mt) {
                int ra = wm * 64 + mt * 16 + (lane & 15);
                af[mt] = *reinterpret_cast<const f16x8*>(&Al[cur][ra * 64 + ((gidx ^ (ra & 7)) * 8)]);
            }
            #pragma unroll
            for (int ntf = 0; ntf < 4; ++ntf) {
                int rb = wn * 64 + ntf * 16 + (lane & 15);
                bf[ntf] = dq8(Blu[cur][rb * 8 + (gidx ^ (rb & 7))], s2v[ntf]);
            }
            #pragma unroll
            for (int mt = 0; mt < 4; ++mt)
                #pragma unroll
                for (int ntf = 0; ntf < 4; ++ntf)
                    acc[mt][ntf] = __builtin_amdgcn_mfma_f32_16x16x32_f16(af[mt], bf[ntf], acc[mt][ntf], 0, 0, 0);
        }
        if (kt < 31) {
            #pragma unroll
            for (int j = 0; j < 4; ++j) *reinterpret_cast<f16x8*>(&Al[cur ^ 1][aoff[j]]) = areg[j];
            #pragma unroll
            for (int j = 0; j < 4; ++j) Blu[cur ^ 1][tid + j * 256] = breg[j];
        }
        __syncthreads();   // one barrier/iter: covers ds_writes of next buf + reads of cur buf
    }

    // epilogue: SwiGLU (even 16-row B-tile = gate, odd = up) + scatter
    const int rbase = (lane >> 4) * 4;
    const int cn = lane & 15;
    #pragma unroll
    for (int mt = 0; mt < 4; ++mt) {
        #pragma unroll
        for (int j = 0; j < 2; ++j) {
            floatx4 g = acc[mt][2 * j];
            floatx4 u = acc[mt][2 * j + 1];
            int col = nt * 64 + (wn * 2 + j) * 16 + cn;
            #pragma unroll
            for (int r = 0; r < 4; ++r) {
                int lrow = wm * 64 + mt * 16 + rbase + r;
                if (m0 + lrow < cnt) {
                    float gate = g[r], up = u[r];
                    float a = gate / (1.f + __expf(-gate)) * up;
                    act[(size_t)meta[lrow] * I_DIM + col] = (f16)a;
                }
            }
        }
    }
}

// ---------------- GEMM2: 128m x 64h, double-buffered + register prefetch ----------------
__global__ __launch_bounds__(256) void gemm2_kernel(
    const f16*      __restrict__ act,
    const unsigned* __restrict__ qpk,
    const float*    __restrict__ sc,     // [E][2048][11]
    const int*      __restrict__ counts,
    const int*      __restrict__ lists,
    const float*    __restrict__ wlists,
    float*          __restrict__ tmp)
{
    const int e   = blockIdx.z;
    const int cnt = counts[e];
    const int m0  = blockIdx.y * 128;
    if (m0 >= cnt) return;
    const int nt  = blockIdx.x;

    __shared__ __align__(16) f16 Al[2][8192];
    __shared__ unsigned Blu[2][512];
    __shared__ float scl[64 * 12];
    __shared__ int   meta[128];
    __shared__ float wmeta[128];

    const int tid = threadIdx.x;
    if (tid < 128) {
        int m = m0 + tid;
        int mm = (m < cnt) ? m : 0;
        meta[tid]  = lists[e * T_TOKENS + mm];
        wmeta[tid] = wlists[e * T_TOKENS + mm];
    }
    for (int i = tid; i < 704; i += 256) {
        int r = i / 11, grp = i - r * 11;
        scl[r * 12 + grp] = sc[(size_t)(e * 2048 + nt * 64 + r) * 11 + grp];
    }
    __syncthreads();

    const int lane = tid & 63;
    const int wv = tid >> 6;
    const int wm = wv >> 1, wn = wv & 1;

    int    aoff[4];
    size_t agbl[4];
    #pragma unroll
    for (int j = 0; j < 4; ++j) {
        int g = tid + 256 * j;
        int arow = g >> 3, cg = g & 7;
        aoff[j] = arow * 64 + ((cg ^ (arow & 7)) * 8);
        agbl[j] = (size_t)meta[arow] * I_DIM + cg * 8;
    }
    const unsigned* bt = qpk + ((size_t)e * 32 + nt) * (22 * 512);

    floatx4 acc[4][2];
    #pragma unroll
    for (int i = 0; i < 4; ++i)
        #pragma unroll
        for (int j = 0; j < 2; ++j)
            acc[i][j] = (floatx4){0.f, 0.f, 0.f, 0.f};

    f16x8    areg[4];
    unsigned breg[2];
    #pragma unroll
    for (int j = 0; j < 4; ++j) areg[j] = *reinterpret_cast<const f16x8*>(act + agbl[j]);
    #pragma unroll
    for (int j = 0; j < 2; ++j) breg[j] = bt[tid + j * 256];
    #pragma unroll
    for (int j = 0; j < 4; ++j) *reinterpret_cast<f16x8*>(&Al[0][aoff[j]]) = areg[j];
    #pragma unroll
    for (int j = 0; j < 2; ++j) Blu[0][tid + j * 256] = breg[j];
    __syncthreads();

    for (int kt = 0; kt < 22; ++kt) {
        const int cur = kt & 1;
        if (kt < 21) {
            #pragma unroll
            for (int j = 0; j < 4; ++j)
                areg[j] = *reinterpret_cast<const f16x8*>(act + agbl[j] + (kt + 1) * 64);
            #pragma unroll
            for (int j = 0; j < 2; ++j)
                breg[j] = bt[(kt + 1) * 512 + tid + j * 256];
        }
        const int grp = kt >> 1;
        __half2 s2v[2];
        #pragma unroll
        for (int ntf = 0; ntf < 2; ++ntf)
            s2v[ntf] = __float2half2_rn(scl[(wn * 32 + ntf * 16 + (lane & 15)) * 12 + grp]);

        #pragma unroll
        for (int ks = 0; ks < 2; ++ks) {
            const int gidx = ks * 4 + (lane >> 4);
            f16x8 af[4], bf[2];
            #pragma unroll
            for (int mt = 0; mt < 4; ++mt) {
                int ra = wm * 64 + mt * 16 + (lane & 15);
                af[mt] = *reinterpret_cast<const f16x8*>(&Al[cur][ra * 64 + ((gidx ^ (ra & 7)) * 8)]);
            }
            #pragma unroll
            for (int ntf = 0; ntf < 2; ++ntf) {
                int rb = wn * 32 + ntf * 16 + (lane & 15);
                bf[ntf] = dq8(Blu[cur][rb * 8 + (gidx ^ (rb & 7))], s2v[ntf]);
            }
            #pragma unroll
            for (int mt = 0; mt < 4; ++mt)
                #pragma unroll
                for (int ntf = 0; ntf < 2; ++ntf)
                    acc[mt][ntf] = __builtin_amdgcn_mfma_f32_16x16x32_f16(af[mt], bf[ntf], acc[mt][ntf], 0, 0, 0);
        }
        if (kt < 21) {
            #pragma unroll
            for (int j = 0; j < 4; ++j) *reinterpret_cast<f16x8*>(&Al[cur ^ 1][aoff[j]]) = areg[j];
            #pragma unroll
            for (int j = 0; j < 2; ++j) Blu[cur ^ 1][tid + j * 256] = breg[j];
        }
        __syncthreads();
    }

    const int rbase = (lane >> 4) * 4;
    const int cn = lane & 15;
    #pragma unroll
    for (int mt = 0; mt < 4; ++mt) {
        #pragma unroll
        for (int ntf = 0; ntf < 2; ++ntf) {
            floatx4 v = acc[mt][ntf];
            int col = nt * 64 + wn * 32 + ntf * 16 + cn;
            #pragma unroll
            for (int r = 0; r < 4; ++r) {
                int lrow = wm * 64 + mt * 16 + rbase + r;
                if (m0 + lrow < cnt) {
                    tmp[(size_t)meta[lrow] * H_DIM + col] = wmeta[lrow] * v[r];
                }
            }
        }
    }
}

// ---------------- finalize: out[t] = tmp[2t] + tmp[2t+1] ----------------
__global__ void finalize_kernel(const float* __restrict__ tmp, float* __restrict__ out)
{
    int i4 = blockIdx.x * blockDim.x + threadIdx.x;
    int t  = i4 >> 9;
    int h  = (i4 & 511) * 4;
    float4 a = *reinterpret_cast<const float4*>(tmp + ((size_t)2 * t) * H_DIM + h);
    float4 b = *reinterpret_cast<const float4*>(tmp + ((size_t)(2 * t + 1)) * H_DIM + h);
    float4 o;
    o.x = a.x + b.x; o.y = a.y + b.y; o.z = a.z + b.z; o.w = a.w + b.w;
    *reinterpret_cast<float4*>(out + (size_t)t * H_DIM + h) = o;
}

extern "C" void kernel_launch(void* const* d_in, const int* in_sizes, int n_in,
                              void* d_out, int out_size, void* d_ws, size_t ws_size,
                              hipStream_t stream)
{
    const float* router_logits = (const float*)d_in[0];
    const float* x             = (const float*)d_in[1];
    const int*   gu_q          = (const int*)d_in[2];
    const float* gu_s          = (const float*)d_in[3];
    const int*   dn_q          = (const int*)d_in[4];
    const float* dn_s          = (const float*)d_in[5];
    float* out = (float*)d_out;

    char* ws = (char*)d_ws;
    int*      counts = (int*)(ws + OFF_COUNTS);
    int*      lists  = (int*)(ws + OFF_LISTS);
    float*    wlists = (float*)(ws + OFF_WLISTS);
    f16*      xb     = (f16*)(ws + OFF_XB);
    f16*      act    = (f16*)(ws + OFF_ACT);
    unsigned* gu_pk  = (unsigned*)(ws + OFF_GUPK);
    unsigned* dn_pk  = (unsigned*)(ws + OFF_DNPK);
    float*    tmp    = (float*)(ws + OFF_TMP);

    hipMemsetAsync(counts, 0, E_NUM * sizeof(int), stream);

    pack_gu_kernel<<<E_NUM * 2816, 256, 0, stream>>>(gu_q, gu_pk);
    pack_dn_kernel<<<E_NUM * 2048, 256, 0, stream>>>(dn_q, dn_pk);
    xconv_kernel<<<T_TOKENS * H_DIM / 8 / 256, 256, 0, stream>>>(x, xb);
    router_kernel<<<T_TOKENS / 256, 256, 0, stream>>>(router_logits, counts, lists, wlists);

    gemm1_kernel<<<dim3(22, 16, 8), 256, 0, stream>>>(xb, gu_pk, gu_s, counts, lists, act);
    gemm2_kernel<<<dim3(32, 16, 8), 256, 0, stream>>>(act, dn_pk, dn_s, counts, lists, wlists, tmp);
    finalize_kernel<<<4096, 256, 0, stream>>>(tmp, out);
}